// Round 1
// 228.437 us; speedup vs baseline: 1.0661x; 1.0661x over previous
//
#include <hip/hip_runtime.h>
#include <hip/hip_bf16.h>
#include <cstddef>

typedef __bf16 bf16x8 __attribute__((ext_vector_type(8)));
typedef float f32x4 __attribute__((ext_vector_type(4)));

// ---------------- prep kernels ----------------

// x fp32 NCHW [8,512,8,8] -> bf16 NHWC [8,8,8,512]
__global__ void convert_x_kernel(const float* __restrict__ x, __hip_bfloat16* __restrict__ act0) {
    int t = blockIdx.x * 256 + threadIdx.x;          // 262144 total
    int c = t & 511; int rest = t >> 9;
    int w = rest & 7; rest >>= 3; int h = rest & 7; int b = rest >> 3;
    act0[t] = __float2bfloat16(x[((b * 512 + c) * 8 + h) * 8 + w]);
}

// Weight transposes fused:
//   w1-w3: fp32 [CO][CI][3][3] -> bf16 [9][CO][CI]  (LDS-staged path, unchanged)
//   w4,w5: fp32 [64][64][3][3] -> bf16 packed B-fragment order [tap][nt][ch][lane][8]
//          (lane = q*16+r; co = nt*16+r; ci = ch*32+q*8+j) -> direct global->VGPR MFMA operand
//   wf:    fp32 [3][64][3][3]  -> bf16 packed [tap][ch][lane][8], co padded 3->16 (co=r)
__global__ void wtrans_all_kernel(const float* __restrict__ w1, __hip_bfloat16* __restrict__ o1,
                                  const float* __restrict__ w2, __hip_bfloat16* __restrict__ o2,
                                  const float* __restrict__ w3, __hip_bfloat16* __restrict__ o3,
                                  const float* __restrict__ w4, __hip_bfloat16* __restrict__ o4,
                                  const float* __restrict__ w5, __hip_bfloat16* __restrict__ o5,
                                  const float* __restrict__ wf, __hip_bfloat16* __restrict__ of) {
    int t = blockIdx.x * 256 + threadIdx.x;
    if (t >= 1631232) return;
    if (t < 1548288) {
        // old-style [9][CO][CI] for stages 1-3
        const float* w; __hip_bfloat16* o; int lgci, lgco;
        if      (t < 1179648) { w = w1; o = o1; lgci = 9; lgco = 8; }
        else if (t < 1474560) { t -= 1179648; w = w2; o = o2; lgci = 8; lgco = 7; }
        else                  { t -= 1474560; w = w3; o = o3; lgci = 7; lgco = 6; }
        int CI = 1 << lgci;
        int ci = t & (CI - 1);
        int co = (t >> lgci) & ((1 << lgco) - 1);
        int tap = t >> (lgci + lgco);
        o[t] = __float2bfloat16(w[((size_t)co * CI + ci) * 9 + tap]);
    } else if (t < 1622016) {
        // packed B-fragment layout for stages 4/5 (36864 elems each)
        const float* w; __hip_bfloat16* o;
        if (t < 1585152) { t -= 1548288; w = w4; o = o4; }
        else             { t -= 1585152; w = w5; o = o5; }
        int j  = t & 7;
        int ln = (t >> 3) & 63;
        int ch = (t >> 9) & 1;
        int nt = (t >> 10) & 3;
        int tap = t >> 12;
        int rr = ln & 15, qq = ln >> 4;
        int co = nt * 16 + rr;
        int ci = ch * 32 + qq * 8 + j;
        o[t] = __float2bfloat16(w[((size_t)co * 64 + ci) * 9 + tap]);
    } else {
        // packed final-conv layout (9216 elems), co padded 3->16
        int u = t - 1622016;
        int j  = u & 7;
        int ln = (u >> 3) & 63;
        int ch = (u >> 9) & 1;
        int tap = u >> 10;
        int rr = ln & 15, qq = ln >> 4;
        int ci = ch * 32 + qq * 8 + j;
        float v = (rr < 3) ? wf[((size_t)rr * 64 + ci) * 9 + tap] : 0.f;
        of[u] = __float2bfloat16(v);
    }
}

// All style FCs fused. S laid out contiguously: S1@0 (8x256), S2@2048 (8x128),
// S3@3072, S4@3584, S5@4096 (8x64 each). One wave per (stage,b,o) -> 4608 waves.
__global__ void style_all_kernel(const float* __restrict__ style,
                                 const float* __restrict__ fw1, const float* __restrict__ fb1,
                                 const float* __restrict__ fw2, const float* __restrict__ fb2,
                                 const float* __restrict__ fw3, const float* __restrict__ fb3,
                                 const float* __restrict__ fw4, const float* __restrict__ fb4,
                                 const float* __restrict__ fw5, const float* __restrict__ fb5,
                                 float* __restrict__ S) {
    int wvid = blockIdx.x * 4 + (threadIdx.x >> 6);
    int lane = threadIdx.x & 63;
    const float* fw; const float* fb; int lg, sOff, local;
    if      (wvid < 2048) { fw = fw1; fb = fb1; lg = 8; sOff = 0;    local = wvid; }
    else if (wvid < 3072) { fw = fw2; fb = fb2; lg = 7; sOff = 2048; local = wvid - 2048; }
    else if (wvid < 3584) { fw = fw3; fb = fb3; lg = 6; sOff = 3072; local = wvid - 3072; }
    else if (wvid < 4096) { fw = fw4; fb = fb4; lg = 6; sOff = 3584; local = wvid - 3584; }
    else                  { fw = fw5; fb = fb5; lg = 6; sOff = 4096; local = wvid - 4096; }
    int b = local >> lg, o = local & ((1 << lg) - 1);
    const float* sb = style + b * 512;
    const float* fwo = fw + (size_t)o * 512;
    float p = 0.f;
    #pragma unroll
    for (int k = lane; k < 512; k += 64) p += sb[k] * fwo[k];
    #pragma unroll
    for (int off = 32; off > 0; off >>= 1) p += __shfl_down(p, off);
    if (lane == 0) S[sOff + local] = p + fb[o];
}

// ---------------- K-split partial conv (stages 1-3, unchanged) ----------------
// Each block: 16x16 output patch x 64 co x one 64-ci slice (blockIdx.z); fp32 partials.
template <int CI, int CO, int HS, int WS>
__launch_bounds__(256)
__global__ void conv_partial_kernel(const __hip_bfloat16* __restrict__ actIn,
                                    const __hip_bfloat16* __restrict__ wtr,
                                    float* __restrict__ Part) {
    constexpr int HO = HS * 2, WO = WS * 2;
    constexpr size_t sliceN = (size_t)8 * HO * WO * CO;
    const int tid = threadIdx.x;
    const int lane = tid & 63, wv = tid >> 6;
    const int r = lane & 15, q = lane >> 4;
    const int pw = WO / 16, ppb = (HO / 16) * pw;
    const int b = blockIdx.x / ppb;
    const int prest = blockIdx.x - b * ppb;
    const int ph = prest / pw, pwi = prest - ph * pw;
    const int oh0 = ph * 16, ow0 = pwi * 16;
    const int sh0 = oh0 >> 1, sw0 = ow0 >> 1;
    const int n0 = blockIdx.y * 64;
    const int ciOff = blockIdx.z * 64;

    __shared__ alignas(16) __hip_bfloat16 Tile[100 * 72];
    __shared__ alignas(16) __hip_bfloat16 Wlds[2][64 * 72];

    f32x4 acc[4][4];
    #pragma unroll
    for (int i = 0; i < 4; ++i)
        #pragma unroll
        for (int j = 0; j < 4; ++j) acc[i][j] = f32x4{0.f, 0.f, 0.f, 0.f};

    // stage A tile (100 px x 64 ci, padded stride 72)
    for (int i = tid; i < 800; i += 256) {
        int pix = i >> 3, koct = i & 7;
        int tr = pix / 10, tc2 = pix - tr * 10;
        int su = sh0 - 1 + tr, sv = sw0 - 1 + tc2;
        uint4 v = {0, 0, 0, 0};
        if (su >= 0 && su < HS && sv >= 0 && sv < WS)
            v = *(const uint4*)(actIn + ((size_t)((b * HS + su) * WS + sv) * CI + ciOff + koct * 8));
        *(uint4*)&Tile[pix * 72 + koct * 8] = v;
    }
    // stage tap-0 weights
    for (int i = tid; i < 512; i += 256) {
        int co = i >> 3, koct = i & 7;
        *(uint4*)&Wlds[0][co * 72 + koct * 8] =
            *(const uint4*)(wtr + ((size_t)(n0 + co)) * CI + ciOff + koct * 8);
    }
    __syncthreads();

    #pragma unroll 1
    for (int tap = 0; tap < 9; ++tap) {
        const bool pf = (tap < 8);
        uint4 wr0 = {0,0,0,0}, wr1 = {0,0,0,0};
        if (pf) {
            int co0 = tid >> 3, k0 = tid & 7;
            wr0 = *(const uint4*)(wtr + ((size_t)(tap + 1) * CO + n0 + co0) * CI + ciOff + k0 * 8);
            int i1 = tid + 256; int co1 = i1 >> 3, k1 = i1 & 7;
            wr1 = *(const uint4*)(wtr + ((size_t)(tap + 1) * CO + n0 + co1) * CI + ciOff + k1 * 8);
        }
        const int dyv = tap / 3;
        const int dxm1 = tap - dyv * 3 - 1;
        const int tc = ((r + dxm1) >> 1) + 1;
        int apix[4];
        #pragma unroll
        for (int mt = 0; mt < 4; ++mt)
            apix[mt] = ((((wv * 4 + mt) + dyv - 1) >> 1) + 1) * 10 + tc;

        const int buf = tap & 1;
        #pragma unroll
        for (int ch = 0; ch < 2; ++ch) {
            bf16x8 af[4], bfr[4];
            #pragma unroll
            for (int mt = 0; mt < 4; ++mt)
                af[mt] = *(const bf16x8*)&Tile[apix[mt] * 72 + ch * 32 + q * 8];
            #pragma unroll
            for (int nt = 0; nt < 4; ++nt)
                bfr[nt] = *(const bf16x8*)&Wlds[buf][(nt * 16 + r) * 72 + ch * 32 + q * 8];
            #pragma unroll
            for (int mt = 0; mt < 4; ++mt)
                #pragma unroll
                for (int nt = 0; nt < 4; ++nt)
                    acc[mt][nt] = __builtin_amdgcn_mfma_f32_16x16x32_bf16(
                        af[mt], bfr[nt], acc[mt][nt], 0, 0, 0);
        }
        if (pf) {
            int nb = buf ^ 1;
            { int co0 = tid >> 3, k0 = tid & 7;
              *(uint4*)&Wlds[nb][co0 * 72 + k0 * 8] = wr0; }
            { int i1 = tid + 256; int co1 = i1 >> 3, k1 = i1 & 7;
              *(uint4*)&Wlds[nb][co1 * 72 + k1 * 8] = wr1; }
            __syncthreads();
        }
    }

    // fp32 partial write, NHWC within slice
    float* P = Part + (size_t)blockIdx.z * sliceN;
    #pragma unroll
    for (int mt = 0; mt < 4; ++mt) {
        const int prow = wv * 4 + mt;
        #pragma unroll
        for (int t2 = 0; t2 < 4; ++t2) {
            const int pcol = q * 4 + t2;
            const size_t obase = ((size_t)(b * HO + oh0 + prow) * WO + ow0 + pcol) * CO + n0;
            #pragma unroll
            for (int nt = 0; nt < 4; ++nt)
                P[obase + nt * 16 + r] = acc[mt][nt][t2];
        }
    }
}

// sum KS fp32 partial slices -> scale + relu -> bf16 NHWC
template <int KS, int CO, int HW>
__launch_bounds__(256)
__global__ void reduce_kernel(const float* __restrict__ Part, const float* __restrict__ S,
                              __hip_bfloat16* __restrict__ actOut) {
    constexpr size_t sliceN = (size_t)8 * HW * CO;
    size_t e = ((size_t)blockIdx.x * 256 + threadIdx.x) * 4;
    if (e >= sliceN) return;
    f32x4 sum = {0.f, 0.f, 0.f, 0.f};
    #pragma unroll
    for (int k = 0; k < KS; ++k) sum += *(const f32x4*)(Part + (size_t)k * sliceN + e);
    const int co = (int)(e & (CO - 1));
    const int b = (int)(e / ((size_t)HW * CO));
    const float* Sb = S + b * CO + co;
    union { ushort4 u; __hip_bfloat16 h[4]; } pack;
    #pragma unroll
    for (int j = 0; j < 4; ++j)
        pack.h[j] = __float2bfloat16(fmaxf(sum[j] * Sb[j], 0.f));
    *(ushort4*)((unsigned short*)actOut + e) = pack.u;
}

// ---------------- fused conv, stages 4-5 (CI=CO=64) ----------------
// B-fragments come straight from global (L1/L2-resident packed weights, 72 KB),
// register double-buffered one tap ahead. A-tile staged to LDS ONCE; the 9-tap
// K-loop has NO barriers and NO LDS writes.
template <int HS, int WS>
__launch_bounds__(256)
__global__ void conv_patch_kernel(const __hip_bfloat16* __restrict__ actIn,
                                  const __hip_bfloat16* __restrict__ wpk,
                                  const float* __restrict__ S,
                                  __hip_bfloat16* __restrict__ actOut) {
    constexpr int HO = HS * 2, WO = WS * 2;

    const int tid = threadIdx.x;
    const int lane = tid & 63, wv = tid >> 6;
    const int r = lane & 15, q = lane >> 4;
    const int lane8 = lane * 8;

    const int pw = WO / 16, ppb = (HO / 16) * pw;
    const int b = blockIdx.x / ppb;
    const int prest = blockIdx.x - b * ppb;
    const int ph = prest / pw, pwi = prest - ph * pw;
    const int oh0 = ph * 16, ow0 = pwi * 16;
    const int sh0 = oh0 >> 1, sw0 = ow0 >> 1;

    __shared__ alignas(16) __hip_bfloat16 Tile[100 * 72];

    f32x4 acc[4][4];
    #pragma unroll
    for (int i = 0; i < 4; ++i)
        #pragma unroll
        for (int j = 0; j < 4; ++j) acc[i][j] = f32x4{0.f, 0.f, 0.f, 0.f};

    const int wv4 = wv * 4;

    // stage source tile once (100 px x 64 ci, padded stride 72)
    for (int i = tid; i < 800; i += 256) {
        int pix = i >> 3, koct = i & 7;
        int tr = pix / 10, tc2 = pix - tr * 10;
        int su = sh0 - 1 + tr, sv = sw0 - 1 + tc2;
        uint4 v = {0, 0, 0, 0};
        if (su >= 0 && su < HS && sv >= 0 && sv < WS)
            v = *(const uint4*)(actIn + ((size_t)((b * HS + su) * WS + sv) * 64 + koct * 8));
        *(uint4*)&Tile[pix * 72 + koct * 8] = v;
    }
    __syncthreads();

    bf16x8 bA[4][2], bB[4][2];

    auto loadB = [&](bf16x8 (&dst)[4][2], int tap) {
        #pragma unroll
        for (int nt = 0; nt < 4; ++nt)
            #pragma unroll
            for (int ch = 0; ch < 2; ++ch)
                dst[nt][ch] = *(const bf16x8*)(wpk + ((tap * 8 + nt * 2 + ch) << 9) + lane8);
    };

    auto compute = [&](int tap, bf16x8 (&bfr)[4][2]) {
        const int dyv = tap / 3;
        const int dxm1 = tap - dyv * 3 - 1;
        const int tc = ((r + dxm1) >> 1) + 1;
        int apix[4];
        #pragma unroll
        for (int mt = 0; mt < 4; ++mt)
            apix[mt] = ((((wv4 + mt) + dyv - 1) >> 1) + 1) * 10 + tc;
        #pragma unroll
        for (int ch = 0; ch < 2; ++ch) {
            bf16x8 af[4];
            #pragma unroll
            for (int mt = 0; mt < 4; ++mt)
                af[mt] = *(const bf16x8*)&Tile[apix[mt] * 72 + ch * 32 + q * 8];
            #pragma unroll
            for (int mt = 0; mt < 4; ++mt)
                #pragma unroll
                for (int nt = 0; nt < 4; ++nt)
                    acc[mt][nt] = __builtin_amdgcn_mfma_f32_16x16x32_bf16(
                        af[mt], bfr[nt][ch], acc[mt][nt], 0, 0, 0);
        }
    };

    loadB(bA, 0);
    #pragma unroll 1
    for (int it = 0; it < 4; ++it) {
        loadB(bB, 2 * it + 1);
        compute(2 * it, bA);
        loadB(bA, 2 * it + 2);          // taps 2,4,6,8
        compute(2 * it + 1, bB);
    }
    compute(8, bA);

    float sv_[4];
    #pragma unroll
    for (int nt = 0; nt < 4; ++nt) sv_[nt] = S[b * 64 + nt * 16 + r];
    #pragma unroll
    for (int mt = 0; mt < 4; ++mt) {
        const int prow = wv4 + mt;
        #pragma unroll
        for (int t2 = 0; t2 < 4; ++t2) {
            const int pcol = q * 4 + t2;
            const size_t obase = ((size_t)(b * HO + oh0 + prow) * WO + ow0 + pcol) * 64;
            #pragma unroll
            for (int nt = 0; nt < 4; ++nt)
                actOut[obase + nt * 16 + r] =
                    __float2bfloat16(fmaxf(acc[mt][nt][t2] * sv_[nt], 0.f));
        }
    }
}

// ---------------- final conv: 64->3 at 256x256, +bias, fp32 NCHW out ----------------
// Weights (18 KB packed) direct from global; LDS holds only the activation tile
// (26 KB vs 49 KB before -> ~2x resident blocks for this streaming kernel).
__launch_bounds__(256)
__global__ void conv_final_kernel(const __hip_bfloat16* __restrict__ actIn, // [8][256][256][64]
                                  const __hip_bfloat16* __restrict__ wpkF, // packed [9][2][64][8]
                                  const float* __restrict__ bias,
                                  float* __restrict__ out) {               // [8][3][256][256]
    constexpr int HO = 256, WO = 256;
    const int tid = threadIdx.x, lane = tid & 63, wv = tid >> 6;
    const int r = lane & 15, q = lane >> 4;
    const int lane8 = lane * 8;

    const int ppb = 32 * 16;
    const int b = blockIdx.x / ppb;
    const int prest = blockIdx.x - b * ppb;
    const int ph = prest >> 4, pwi = prest & 15;
    const int oh0 = ph * 8, ow0 = pwi * 16;

    __shared__ alignas(16) __hip_bfloat16 Tile[10 * 18 * 72];

    for (int i = tid; i < 1440; i += 256) {
        int pix = i >> 3, koct = i & 7;
        int tr = pix / 18, tc2 = pix - tr * 18;
        int u = oh0 - 1 + tr, v = ow0 - 1 + tc2;
        uint4 val = {0, 0, 0, 0};
        if (u >= 0 && u < HO && v >= 0 && v < WO)
            val = *(const uint4*)(actIn + ((size_t)((b * HO + u) * WO + v) * 64 + koct * 8));
        *(uint4*)&Tile[pix * 72 + koct * 8] = val;
    }
    __syncthreads();

    f32x4 acc[2];
    acc[0] = f32x4{0.f, 0.f, 0.f, 0.f};
    acc[1] = f32x4{0.f, 0.f, 0.f, 0.f};

    #pragma unroll 1
    for (int tap = 0; tap < 9; ++tap) {
        const int dyv = tap / 3;
        const int dxv = tap - dyv * 3;
        const int tc = r + dxv;
        int apix[2];
        #pragma unroll
        for (int mt = 0; mt < 2; ++mt)
            apix[mt] = (wv * 2 + mt + dyv) * 18 + tc;
        #pragma unroll
        for (int ch = 0; ch < 2; ++ch) {
            bf16x8 bfr = *(const bf16x8*)(wpkF + ((tap * 2 + ch) << 9) + lane8);
            #pragma unroll
            for (int mt = 0; mt < 2; ++mt) {
                bf16x8 af = *(const bf16x8*)&Tile[apix[mt] * 72 + ch * 32 + q * 8];
                acc[mt] = __builtin_amdgcn_mfma_f32_16x16x32_bf16(af, bfr, acc[mt], 0, 0, 0);
            }
        }
    }

    if (r < 3) {
        const float bs = bias[r];
        #pragma unroll
        for (int mt = 0; mt < 2; ++mt) {
            const int prow = wv * 2 + mt;
            #pragma unroll
            for (int t2 = 0; t2 < 4; ++t2) {
                const int pcol = q * 4 + t2;
                out[((size_t)(b * 3 + r) << 16) + (oh0 + prow) * 256 + ow0 + pcol] =
                    acc[mt][t2] + bs;
            }
        }
    }
}

// ---------------- launch ----------------
extern "C" void kernel_launch(void* const* d_in, const int* in_sizes, int n_in,
                              void* d_out, int out_size, void* d_ws, size_t ws_size,
                              hipStream_t stream) {
    const float* x    = (const float*)d_in[0];
    const float* sty  = (const float*)d_in[1];
    const float* w1   = (const float*)d_in[2];
    const float* fw1  = (const float*)d_in[3];
    const float* fb1  = (const float*)d_in[4];
    const float* w2   = (const float*)d_in[5];
    const float* fw2  = (const float*)d_in[6];
    const float* fb2  = (const float*)d_in[7];
    const float* w3   = (const float*)d_in[8];
    const float* fw3  = (const float*)d_in[9];
    const float* fb3  = (const float*)d_in[10];
    const float* w4   = (const float*)d_in[11];
    const float* fw4  = (const float*)d_in[12];
    const float* fb4  = (const float*)d_in[13];
    const float* w5   = (const float*)d_in[14];
    const float* fw5  = (const float*)d_in[15];
    const float* fb5  = (const float*)d_in[16];
    const float* wf   = (const float*)d_in[17];
    const float* bf   = (const float*)d_in[18];
    float* out = (float*)d_out;

    char* ws = (char*)d_ws;
    size_t off = 0;
    auto alloc = [&](size_t bytes) {
        char* p = ws + off;
        off += (bytes + 255) & ~(size_t)255;
        return p;
    };
    // S1..S5 contiguous (all sizes multiples of 256 B) -> fused style kernel writes S1 base
    float* S1 = (float*)alloc(8 * 256 * 4);
    float* S2 = (float*)alloc(8 * 128 * 4);
    float* S3 = (float*)alloc(8 * 64 * 4);
    float* S4 = (float*)alloc(8 * 64 * 4);
    float* S5 = (float*)alloc(8 * 64 * 4);
    __hip_bfloat16* act0 = (__hip_bfloat16*)alloc((size_t)262144 * 2);   // 8x8x8x512
    __hip_bfloat16* act1 = (__hip_bfloat16*)alloc((size_t)524288 * 2);   // 8x16x16x256
    __hip_bfloat16* act2 = (__hip_bfloat16*)alloc((size_t)1048576 * 2);  // 8x32x32x128
    __hip_bfloat16* act3 = (__hip_bfloat16*)alloc((size_t)2097152 * 2);  // 8x64x64x64
    __hip_bfloat16* act4 = (__hip_bfloat16*)alloc((size_t)8388608 * 2);  // 8x128x128x64
    __hip_bfloat16* act5 = (__hip_bfloat16*)alloc((size_t)33554432 * 2); // 8x256x256x64
    __hip_bfloat16* wt1  = (__hip_bfloat16*)alloc((size_t)9 * 256 * 512 * 2);
    __hip_bfloat16* wt2  = (__hip_bfloat16*)alloc((size_t)9 * 128 * 256 * 2);
    __hip_bfloat16* wt3  = (__hip_bfloat16*)alloc((size_t)9 * 64 * 128 * 2);
    __hip_bfloat16* wt4  = (__hip_bfloat16*)alloc((size_t)9 * 64 * 64 * 2);   // packed
    __hip_bfloat16* wt5  = (__hip_bfloat16*)alloc((size_t)9 * 64 * 64 * 2);   // packed
    __hip_bfloat16* wtF  = (__hip_bfloat16*)alloc((size_t)9 * 16 * 64 * 2);   // packed
    if (off > ws_size) return;

    // fp32 K-split partial scratch (16 MB) aliased onto act5 (64 MB, written only by
    // stage 5 which runs after the last reduce) -- no extra ws footprint.
    float* Part = (float*)act5;

    convert_x_kernel<<<1024, 256, 0, stream>>>(x, act0);
    wtrans_all_kernel<<<6372, 256, 0, stream>>>(w1, wt1, w2, wt2, w3, wt3,
                                                w4, wt4, w5, wt5, wf, wtF);
    style_all_kernel<<<1152, 256, 0, stream>>>(sty, fw1, fb1, fw2, fb2, fw3, fb3,
                                               fw4, fb4, fw5, fb5, S1);

    // stages 1-3: K-split partials (256 blocks each) + reduce
    conv_partial_kernel<512, 256, 8, 8><<<dim3(8, 4, 8), 256, 0, stream>>>(act0, wt1, Part);
    reduce_kernel<8, 256, 256><<<512, 256, 0, stream>>>(Part, S1, act1);
    conv_partial_kernel<256, 128, 16, 16><<<dim3(32, 2, 4), 256, 0, stream>>>(act1, wt2, Part);
    reduce_kernel<4, 128, 1024><<<1024, 256, 0, stream>>>(Part, S2, act2);
    conv_partial_kernel<128, 64, 32, 32><<<dim3(128, 1, 2), 256, 0, stream>>>(act2, wt3, Part);
    reduce_kernel<2, 64, 4096><<<2048, 256, 0, stream>>>(Part, S3, act3);

    // stages 4-5: barrier-free fused patch kernel, B-fragments direct from global
    conv_patch_kernel<64, 64><<<dim3(512), 256, 0, stream>>>(act3, wt4, S4, act4);
    conv_patch_kernel<128, 128><<<dim3(2048), 256, 0, stream>>>(act4, wt5, S5, act5);
    conv_final_kernel<<<4096, 256, 0, stream>>>(act5, wtF, bf, out);
}